// Round 1
// baseline (849.829 us; speedup 1.0000x reference)
//
#include <hip/hip_runtime.h>
#include <cstdint>

#define CC 512
#define AA 256

typedef __bf16 bf16x8 __attribute__((ext_vector_type(8)));
typedef float f32x16 __attribute__((ext_vector_type(16)));

__device__ __forceinline__ unsigned short f2bf(float f) {
  union { float f; uint32_t u; } v; v.f = f;
  uint32_t r = (v.u + 0x7FFFu + ((v.u >> 16) & 1u)) >> 16;
  return (unsigned short)r;
}

// ---------------- prep: attn2 = Ua.q + Ua_b + Wa_b ; Wa -> bf16 ; zero ctx ----
__global__ void prep_kernel(const float* __restrict__ q,
                            const float* __restrict__ Wa_w,
                            const float* __restrict__ Wa_b,
                            const float* __restrict__ Ua_w,
                            const float* __restrict__ Ua_b,
                            unsigned short* __restrict__ wa_bf,
                            float* __restrict__ attn2,
                            float* __restrict__ out_ctx) {
  const int blk = blockIdx.x, t = threadIdx.x;
  if (blk < 64) {
    const int b = blk, a = t;  // 256 threads = 256 a values
    float acc = Ua_b[a] + Wa_b[a];
    const float4* qr = (const float4*)(q + (size_t)b * CC);
    const float4* ur = (const float4*)(Ua_w + (size_t)a * CC);
#pragma unroll 4
    for (int i = 0; i < CC / 4; ++i) {
      float4 uu = ur[i]; float4 qq = qr[i];
      acc += uu.x * qq.x + uu.y * qq.y + uu.z * qq.z + uu.w * qq.w;
    }
    attn2[b * AA + a] = acc;
  } else if (blk < 128) {
    const int base = (blk - 64) * 2048 + t * 8;  // 64 blocks * 2048 = 131072
#pragma unroll
    for (int i = 0; i < 8; ++i) wa_bf[base + i] = f2bf(Wa_w[base + i]);
  } else {
    const int base = (blk - 128) * 512 + t * 2;  // zero 32768 context floats
    out_ctx[base] = 0.f; out_ctx[base + 1] = 0.f;
  }
}

// ---------------- scores: s[r] = va . tanh(keys[r].Wa^T + attn2[b]) + va_b ----
// block tile: M=128 rows (r = p*64+b flat), N=256 (all of A), K=512 in BK=64 chunks.
// 4 waves, each 64 rows x 128 cols via 2x4 grid of mfma_f32_32x32x16_bf16.
__global__ __launch_bounds__(256, 2) void scores_kernel(
    const float* __restrict__ keys,
    const unsigned short* __restrict__ wa_bf,
    const float* __restrict__ attn2,
    const float* __restrict__ va_w,
    const float* __restrict__ va_b,
    float* __restrict__ scores) {
  // LDS: As 128x72 bf16 (pad 64->72 keeps b128 reads bank-balanced, 16B aligned)
  //      Bs 256x72 bf16 ; total 55296 B -> 2 blocks/CU
  __shared__ __align__(16) unsigned char smem[55296];
  unsigned short* As = (unsigned short*)smem;
  unsigned short* Bs = As + 128 * 72;

  const int t = threadIdx.x;
  const int w = t >> 6, lane = t & 63;
  const int m32 = lane & 31, kg = lane >> 5;
  const int R0w = (w & 1) * 64, C0w = (w >> 1) * 128;
  const long r0 = (long)blockIdx.x * 128;

  f32x16 acc[2][4];
#pragma unroll
  for (int i = 0; i < 2; ++i)
#pragma unroll
    for (int j = 0; j < 4; ++j)
#pragma unroll
      for (int e = 0; e < 16; ++e) acc[i][j][e] = 0.f;

  const int c4 = t & 15, rg = t >> 4;  // A staging: 16 float4-cols x 16 rows/pass
  const int kq = t & 7, ng = t >> 3;   // B staging: 8 x16B-cols x 32 rows/pass

  for (int ko = 0; ko < 8; ++ko) {
    const int kb = ko * 64;
#pragma unroll
    for (int ps = 0; ps < 8; ++ps) {     // keys fp32 -> bf16 -> LDS
      const int row = rg + ps * 16;
      float4 v = *(const float4*)(keys + (r0 + row) * CC + kb + c4 * 4);
      ushort4 h;
      h.x = f2bf(v.x); h.y = f2bf(v.y); h.z = f2bf(v.z); h.w = f2bf(v.w);
      *(ushort4*)(As + row * 72 + c4 * 4) = h;
    }
#pragma unroll
    for (int ps = 0; ps < 8; ++ps) {     // Wa bf16 -> LDS (16B vec)
      const int n = ng + ps * 32;
      int4 v = *(const int4*)(wa_bf + (size_t)n * CC + kb + kq * 8);
      *(int4*)(Bs + n * 72 + kq * 8) = v;
    }
    __syncthreads();
    for (int kk = 0; kk < 4; ++kk) {
      const int k0 = kk * 16 + kg * 8;
      bf16x8 a0 = *(const bf16x8*)(As + (R0w + m32) * 72 + k0);
      bf16x8 a1 = *(const bf16x8*)(As + (R0w + 32 + m32) * 72 + k0);
      bf16x8 b0 = *(const bf16x8*)(Bs + (C0w + m32) * 72 + k0);
      bf16x8 b1 = *(const bf16x8*)(Bs + (C0w + 32 + m32) * 72 + k0);
      bf16x8 b2 = *(const bf16x8*)(Bs + (C0w + 64 + m32) * 72 + k0);
      bf16x8 b3 = *(const bf16x8*)(Bs + (C0w + 96 + m32) * 72 + k0);
      acc[0][0] = __builtin_amdgcn_mfma_f32_32x32x16_bf16(a0, b0, acc[0][0], 0, 0, 0);
      acc[0][1] = __builtin_amdgcn_mfma_f32_32x32x16_bf16(a0, b1, acc[0][1], 0, 0, 0);
      acc[0][2] = __builtin_amdgcn_mfma_f32_32x32x16_bf16(a0, b2, acc[0][2], 0, 0, 0);
      acc[0][3] = __builtin_amdgcn_mfma_f32_32x32x16_bf16(a0, b3, acc[0][3], 0, 0, 0);
      acc[1][0] = __builtin_amdgcn_mfma_f32_32x32x16_bf16(a1, b0, acc[1][0], 0, 0, 0);
      acc[1][1] = __builtin_amdgcn_mfma_f32_32x32x16_bf16(a1, b1, acc[1][1], 0, 0, 0);
      acc[1][2] = __builtin_amdgcn_mfma_f32_32x32x16_bf16(a1, b2, acc[1][2], 0, 0, 0);
      acc[1][3] = __builtin_amdgcn_mfma_f32_32x32x16_bf16(a1, b3, acc[1][3], 0, 0, 0);
    }
    __syncthreads();
  }

  // ---- epilogue: tanh(acc + attn2[b][a]) * va[a], reduce over a ----
  // C/D layout (m74/m101): col = nt*32 + (lane&31); row = (r&3)+8*(r>>2)+4*kg.
  // b = (r0 + row_local) & 63 = row_local & 63 since r0 % 128 == 0.
  float* sc0 = (float*)smem;      // rows 0..127, cols 0..127 (waves 0,1)
  float* sc1 = sc0 + 128;         // rows 0..127, cols 128..255 (waves 2,3)

#pragma unroll
  for (int mt = 0; mt < 2; ++mt) {
    float ps[16];
#pragma unroll
    for (int r = 0; r < 16; ++r) ps[r] = 0.f;
    const int rowb = R0w + mt * 32 + 4 * kg;
#pragma unroll
    for (int nt = 0; nt < 4; ++nt) {
      const int col = C0w + nt * 32 + m32;
      const float vv = va_w[col];
#pragma unroll
      for (int r = 0; r < 16; ++r) {
        const int row = rowb + (r & 3) + 8 * (r >> 2);
        float x = acc[mt][nt][r] + attn2[(row & 63) * AA + col];
        float ax = fabsf(x);
        float e2 = __expf(-2.f * ax);
        float th = (1.f - e2) / (1.f + e2);
        ps[r] += copysignf(th, x) * vv;
      }
    }
    // reduce over the 32 columns held across lanes (low 5 lane bits)
#pragma unroll
    for (int off = 1; off <= 16; off <<= 1)
#pragma unroll
      for (int r = 0; r < 16; ++r) ps[r] += __shfl_xor(ps[r], off);
    if (m32 == 0) {
      float* dst = (w >> 1) ? sc1 : sc0;
#pragma unroll
      for (int r = 0; r < 16; ++r) dst[rowb + (r & 3) + 8 * (r >> 2)] = ps[r];
    }
  }
  __syncthreads();
  if (t < 128) scores[r0 + t] = sc0[t] + sc1[t] + va_b[0];
}

// ---------------- softmax over P per b; writes weights to d_out+32768 --------
__global__ void softmax_kernel(const float* __restrict__ scores,
                               float* __restrict__ out) {
  const int b = blockIdx.x, t = threadIdx.x;
  const int w = t >> 6, lane = t & 63;
  __shared__ float red[4];
  float s[16];
  float m = -1e30f;
#pragma unroll
  for (int i = 0; i < 16; ++i) {
    s[i] = scores[(size_t)(t + 256 * i) * 64 + b];
    m = fmaxf(m, s[i]);
  }
#pragma unroll
  for (int off = 1; off <= 32; off <<= 1) m = fmaxf(m, __shfl_xor(m, off));
  if (lane == 0) red[w] = m;
  __syncthreads();
  m = fmaxf(fmaxf(red[0], red[1]), fmaxf(red[2], red[3]));
  float sum = 0.f;
#pragma unroll
  for (int i = 0; i < 16; ++i) { s[i] = __expf(s[i] - m); sum += s[i]; }
#pragma unroll
  for (int off = 1; off <= 32; off <<= 1) sum += __shfl_xor(sum, off);
  __syncthreads();
  if (lane == 0) red[w] = sum;
  __syncthreads();
  const float invZ = 1.f / (red[0] + red[1] + red[2] + red[3]);
  float* wout = out + 32768;
#pragma unroll
  for (int i = 0; i < 16; ++i)
    wout[(size_t)(t + 256 * i) * 64 + b] = s[i] * invZ;
}

// ---------------- context[b][c] = sum_p w[p,b] * keys[p,b,c] -----------------
__global__ __launch_bounds__(128) void context_kernel(
    const float* __restrict__ keys,
    const float* __restrict__ wts,   // d_out + 32768
    float* __restrict__ out_ctx) {   // d_out (pre-zeroed by prep)
  const int b = blockIdx.y, pc = blockIdx.x, t = threadIdx.x;
  const int p0 = pc * 128;
  __shared__ float wl[128];
  wl[t] = wts[(size_t)(p0 + t) * 64 + b];
  __syncthreads();
  float4 acc = {0.f, 0.f, 0.f, 0.f};
  const float4* kp = (const float4*)keys;
#pragma unroll 4
  for (int j = 0; j < 128; ++j) {
    float4 kv = kp[(size_t)((p0 + j) * 64 + b) * 128 + t];
    const float wj = wl[j];
    acc.x += wj * kv.x; acc.y += wj * kv.y;
    acc.z += wj * kv.z; acc.w += wj * kv.w;
  }
  float* dst = out_ctx + b * 512 + t * 4;
  atomicAdd(dst + 0, acc.x);
  atomicAdd(dst + 1, acc.y);
  atomicAdd(dst + 2, acc.z);
  atomicAdd(dst + 3, acc.w);
}

extern "C" void kernel_launch(void* const* d_in, const int* in_sizes, int n_in,
                              void* d_out, int out_size, void* d_ws, size_t ws_size,
                              hipStream_t stream) {
  (void)in_sizes; (void)n_in; (void)out_size; (void)ws_size;
  const float* keys = (const float*)d_in[0];
  const float* q    = (const float*)d_in[1];
  const float* Wa_w = (const float*)d_in[2];
  const float* Wa_b = (const float*)d_in[3];
  const float* Ua_w = (const float*)d_in[4];
  const float* Ua_b = (const float*)d_in[5];
  const float* va_w = (const float*)d_in[6];
  const float* va_b = (const float*)d_in[7];
  float* out = (float*)d_out;

  // workspace layout: Wa bf16 (262144 B) | attn2 (65536 B) | scores (1 MiB)
  unsigned short* wa_bf = (unsigned short*)d_ws;
  float* attn2  = (float*)((char*)d_ws + 262144);
  float* scores = (float*)((char*)d_ws + 262144 + 65536);

  prep_kernel<<<192, 256, 0, stream>>>(q, Wa_w, Wa_b, Ua_w, Ua_b, wa_bf, attn2, out);
  scores_kernel<<<2048, 256, 0, stream>>>(keys, wa_bf, attn2, va_w, va_b, scores);
  softmax_kernel<<<64, 256, 0, stream>>>(scores, out);
  context_kernel<<<dim3(32, 64), 128, 0, stream>>>(keys, out + 32768, out);
}